// Round 5
// baseline (288.241 us; speedup 1.0000x reference)
//
#include <hip/hip_runtime.h>
#include <hip/hip_bf16.h>

typedef __attribute__((ext_vector_type(8))) short short8;
typedef __attribute__((ext_vector_type(4))) short short4v;
typedef __attribute__((ext_vector_type(4))) float f32x4;

static inline size_t ws_align(size_t x) { return (x + 511) & ~((size_t)511); }

static __device__ inline unsigned short f2bf(float f) {
    __hip_bfloat16 h = __float2bfloat16(f);
    return __builtin_bit_cast(unsigned short, h);
}
static __device__ inline float bfbits2f(unsigned short u) {
    unsigned x = ((unsigned)u) << 16;
    return __builtin_bit_cast(float, x);
}

// ---------------- inline dtype sniffing (per-wave ballot, no extra kernel) ----------------
// fp32-ness of float inputs: even shorts of real bf16 data have sane exponents;
// fp32 low-halves are uniform garbage.
static __device__ inline int sniff_fp32(const unsigned short* __restrict__ w1) {
    int i = threadIdx.x & 63;
    unsigned e = (w1[2 * i] >> 7) & 0xFF;
    unsigned long long m = __ballot(e >= 100 && e <= 130);
    return (__popcll(m) < 48) ? 1 : 0;
}
// int64-ness of edge_index: odd int32 slots all zero iff int64 (values < 50000).
static __device__ inline int sniff_is64(const unsigned int* __restrict__ ei) {
    int i = threadIdx.x & 63;
    unsigned long long m = __ballot(ei[2 * i + 1] == 0u);
    return (__popcll(m) >= 48) ? 1 : 0;
}

// ---------------- CSR build ----------------
// hist: count + record stable local offset per edge (the atomic's return value).
__global__ void hist_kernel(const int* __restrict__ ei,
                            int* __restrict__ counts, int* __restrict__ loff, int E) {
    int is64 = sniff_is64((const unsigned int*)ei);
    int e = blockIdx.x * blockDim.x + threadIdx.x;
    if (e < E) {
        int d = is64 ? ei[2 * (size_t)E + 2 * e] : ei[(size_t)E + e];
        loff[e] = atomicAdd(&counts[d], 1);
    }
}

// fused: dinv + segment allocation (wave-scan + one atomic per wave).
// rc[n] = (start, len). Order across waves arbitrary — spmm needs per-node contiguity only.
__global__ __launch_bounds__(256) void alloc_kernel(const int* __restrict__ counts,
                                                    float* __restrict__ dinv,
                                                    int2* __restrict__ rc,
                                                    int* __restrict__ total, int N) {
    int n = blockIdx.x * blockDim.x + threadIdx.x;
    int lane = threadIdx.x & 63;
    int c = (n < N) ? counts[n] : 0;
    if (n < N) {
        int d = (c < 1) ? 1 : c;
        dinv[n] = rsqrtf((float)d);
    }
    int incl = c;
#pragma unroll
    for (int off = 1; off < 64; off <<= 1) {
        int v = __shfl_up(incl, off, 64);
        if (lane >= off) incl += v;
    }
    int wavetot = __shfl(incl, 63, 64);
    int base = 0;
    if (lane == 0) base = atomicAdd(total, wavetot);
    base = __shfl(base, 0, 64);
    if (n < N) rc[n] = make_int2(base + incl - c, c);
}

// atomic-free fill: position = segment start + recorded local offset.
__global__ void fill_kernel(const int* __restrict__ ei,
                            const float* __restrict__ dinv, const int2* __restrict__ rc,
                            const int* __restrict__ loff, int2* __restrict__ edgedat, int E) {
    int is64 = sniff_is64((const unsigned int*)ei);
    int e = blockIdx.x * blockDim.x + threadIdx.x;
    if (e < E) {
        int s, d;
        if (is64) {
            s = ei[2 * e];
            d = ei[2 * (size_t)E + 2 * e];
        } else {
            s = ei[e];
            d = ei[(size_t)E + e];
        }
        int pos = rc[d].x + loff[e];
        float wt = dinv[s] * dinv[d];
        edgedat[pos] = make_int2(s, __float_as_int(wt));
    }
}

// ---------------- GEMM: out[N x FOUT] = A[N x 128] @ W[128 x FOUT], bf16 MFMA ----------------
// 256 threads = 4 waves; each wave computes 2 row-tiles of 16 -> 128 rows/block.

template <int FOUT>
__global__ __launch_bounds__(256) void gemm_kernel(const void* __restrict__ Araw, int a_follows,
                                                   const void* __restrict__ Wraw,
                                                   const unsigned short* __restrict__ w1sniff,
                                                   unsigned short* __restrict__ out, int Nrows) {
    constexpr int K = 128;
    constexpr int NT = FOUT / 16;
    constexpr int LDB = K + 8;
    __shared__ __align__(16) unsigned short bt[FOUT * LDB];  // bt[n][k] = W[k][n]

    const int tid = threadIdx.x;
    const int in_fp32 = sniff_fp32(w1sniff);
    const int a_fp32 = a_follows & in_fp32;

    constexpr int TOT4 = K * FOUT / 4;
    if (in_fp32) {
        const float* Wf = (const float*)Wraw;
        for (int i = tid; i < TOT4; i += 256) {
            int idx = i * 4;
            int k = idx / FOUT;
            int n = idx & (FOUT - 1);
            float4 v = *(const float4*)(const void*)(Wf + idx);
            bt[(n + 0) * LDB + k] = f2bf(v.x);
            bt[(n + 1) * LDB + k] = f2bf(v.y);
            bt[(n + 2) * LDB + k] = f2bf(v.z);
            bt[(n + 3) * LDB + k] = f2bf(v.w);
        }
    } else {
        const unsigned short* Ws = (const unsigned short*)Wraw;
        for (int i = tid; i < TOT4; i += 256) {
            int idx = i * 4;
            int k = idx / FOUT;
            int n = idx & (FOUT - 1);
            short4v v = *(const short4v*)(const void*)(Ws + idx);
#pragma unroll
            for (int j = 0; j < 4; j++) bt[(n + j) * LDB + k] = ((const unsigned short*)&v)[j];
        }
    }

    const int wave = tid >> 6;
    const int lane = tid & 63;
    const int quad = lane >> 4;
    const int r16 = lane & 15;

    short8 afrag[2][4];
#pragma unroll
    for (int t = 0; t < 2; t++) {
        int arow = blockIdx.x * 128 + t * 64 + wave * 16 + r16;
        if (arow > Nrows - 1) arow = Nrows - 1;
        if (a_fp32) {
            const float* Ap = (const float*)Araw + (size_t)arow * K + quad * 8;
#pragma unroll
            for (int kk = 0; kk < 4; kk++) {
                float4 f0 = *(const float4*)(const void*)(Ap + kk * 32);
                float4 f1 = *(const float4*)(const void*)(Ap + kk * 32 + 4);
                short8 r;
                r[0] = (short)f2bf(f0.x); r[1] = (short)f2bf(f0.y);
                r[2] = (short)f2bf(f0.z); r[3] = (short)f2bf(f0.w);
                r[4] = (short)f2bf(f1.x); r[5] = (short)f2bf(f1.y);
                r[6] = (short)f2bf(f1.z); r[7] = (short)f2bf(f1.w);
                afrag[t][kk] = r;
            }
        } else {
            const unsigned short* Ap = (const unsigned short*)Araw + (size_t)arow * K + quad * 8;
#pragma unroll
            for (int kk = 0; kk < 4; kk++) afrag[t][kk] = *(const short8*)(const void*)(Ap + kk * 32);
        }
    }

    __syncthreads();

    f32x4 acc[2][NT];
#pragma unroll
    for (int t = 0; t < 2; t++)
#pragma unroll
        for (int nt = 0; nt < NT; nt++) acc[t][nt] = (f32x4){0.f, 0.f, 0.f, 0.f};

#pragma unroll
    for (int kk = 0; kk < 4; kk++) {
#pragma unroll
        for (int nt = 0; nt < NT; nt++) {
            short8 b = *(const short8*)(const void*)(&bt[(nt * 16 + r16) * LDB + kk * 32 + quad * 8]);
#pragma unroll
            for (int t = 0; t < 2; t++)
                acc[t][nt] = __builtin_amdgcn_mfma_f32_16x16x32_bf16(afrag[t][kk], b, acc[t][nt], 0, 0, 0);
        }
    }

    // C layout: col = lane&15, row = quad*4 + r. Pack col pairs via shfl_xor; even lanes store bf16x2.
#pragma unroll
    for (int t = 0; t < 2; t++) {
#pragma unroll
        for (int nt = 0; nt < NT; nt++) {
#pragma unroll
            for (int r = 0; r < 4; r++) {
                float v = acc[t][nt][r];
                float o = __shfl_xor(v, 1, 64);
                int row = blockIdx.x * 128 + t * 64 + wave * 16 + quad * 4 + r;
                if (((lane & 1) == 0) && row < Nrows) {
                    __hip_bfloat162 pk;
                    pk.x = __float2bfloat16(v);
                    pk.y = __float2bfloat16(o);
                    *(__hip_bfloat162*)(out + (size_t)row * FOUT + nt * 16 + r16) = pk;
                }
            }
        }
    }
}

// ---------------- SpMM: 2 nodes per wave (32 lanes each), 8-slot masked unroll ----------------
// F=128: lane covers 4 cols (8B gathers). 16 gathers in flight per wave.

__global__ __launch_bounds__(256) void spmm128_kernel(const int2* __restrict__ edgedat,
                                                      const int2* __restrict__ rc,
                                                      const unsigned short* __restrict__ Hin,
                                                      unsigned short* __restrict__ Hout, int N) {
    int wid = (blockIdx.x * 256 + threadIdx.x) >> 6;
    int lane = threadIdx.x & 63;
    int half = lane >> 5;
    int li = lane & 31;
    int n = wid * 2 + half;
    int nc = (n < N) ? n : (N - 1);
    int2 r_ = rc[nc];
    int start = r_.x;
    int len = (n < N) ? r_.y : 0;
    int maxlen = max(len, __shfl_xor(len, 32, 64));

    float a0 = 0.f, a1 = 0.f, a2 = 0.f, a3 = 0.f;
    for (int j = 0; j < maxlen; j += 8) {
        int2 ed[8];
#pragma unroll
        for (int u = 0; u < 8; u++) {
            int jj = j + u;
            int idx = (jj < len) ? (start + jj) : start;
            ed[u] = edgedat[idx];
        }
        short4v hv[8];
#pragma unroll
        for (int u = 0; u < 8; u++) {
            int s = ed[u].x;
            s = (s < 0) ? 0 : ((s > N - 1) ? (N - 1) : s);   // clamp garbage on masked slots
            hv[u] = *(const short4v*)(const void*)(Hin + (size_t)s * 128 + li * 4);
        }
#pragma unroll
        for (int u = 0; u < 8; u++) {
            float w = ((j + u) < len) ? __int_as_float(ed[u].y) : 0.f;
            a0 += w * bfbits2f((unsigned short)hv[u][0]);
            a1 += w * bfbits2f((unsigned short)hv[u][1]);
            a2 += w * bfbits2f((unsigned short)hv[u][2]);
            a3 += w * bfbits2f((unsigned short)hv[u][3]);
        }
    }
    if (n < N) {
        short4v o;
        o[0] = (short)f2bf(fmaxf(a0, 0.f));
        o[1] = (short)f2bf(fmaxf(a1, 0.f));
        o[2] = (short)f2bf(fmaxf(a2, 0.f));
        o[3] = (short)f2bf(fmaxf(a3, 0.f));
        *(short4v*)(Hout + (size_t)n * 128 + li * 4) = o;
    }
}

// F=64 + relu + softmax: lane covers 2 cols; softmax over 32-lane half via xor-shuffles.
__global__ __launch_bounds__(256) void spmm64_softmax_kernel(const int2* __restrict__ edgedat,
                                                             const int2* __restrict__ rc,
                                                             const unsigned short* __restrict__ Hin,
                                                             const unsigned short* __restrict__ w1sniff,
                                                             void* __restrict__ Out, int N) {
    int out_fp32 = sniff_fp32(w1sniff);
    int wid = (blockIdx.x * 256 + threadIdx.x) >> 6;
    int lane = threadIdx.x & 63;
    int half = lane >> 5;
    int li = lane & 31;
    int n = wid * 2 + half;
    int nc = (n < N) ? n : (N - 1);
    int2 r_ = rc[nc];
    int start = r_.x;
    int len = (n < N) ? r_.y : 0;
    int maxlen = max(len, __shfl_xor(len, 32, 64));

    float a0 = 0.f, a1 = 0.f;
    for (int j = 0; j < maxlen; j += 8) {
        int2 ed[8];
#pragma unroll
        for (int u = 0; u < 8; u++) {
            int jj = j + u;
            int idx = (jj < len) ? (start + jj) : start;
            ed[u] = edgedat[idx];
        }
        unsigned hv[8];
#pragma unroll
        for (int u = 0; u < 8; u++) {
            int s = ed[u].x;
            s = (s < 0) ? 0 : ((s > N - 1) ? (N - 1) : s);
            hv[u] = *(const unsigned*)(const void*)(Hin + (size_t)s * 64 + li * 2);
        }
#pragma unroll
        for (int u = 0; u < 8; u++) {
            float w = ((j + u) < len) ? __int_as_float(ed[u].y) : 0.f;
            a0 += w * bfbits2f((unsigned short)(hv[u] & 0xFFFF));
            a1 += w * bfbits2f((unsigned short)(hv[u] >> 16));
        }
    }
    a0 = fmaxf(a0, 0.f);
    a1 = fmaxf(a1, 0.f);
    // softmax over 64 cols = 32 lanes x 2 vals (xor offsets <32 stay within the half)
    float m = fmaxf(a0, a1);
#pragma unroll
    for (int off = 16; off > 0; off >>= 1) m = fmaxf(m, __shfl_xor(m, off, 64));
    float e0 = __expf(a0 - m), e1 = __expf(a1 - m);
    float s = e0 + e1;
#pragma unroll
    for (int off = 16; off > 0; off >>= 1) s += __shfl_xor(s, off, 64);
    float r0 = e0 / s, r1 = e1 / s;
    if (n < N) {
        if (out_fp32) {
            float2 pk = make_float2(r0, r1);
            *(float2*)((float*)Out + (size_t)n * 64 + li * 2) = pk;
        } else {
            unsigned pk = (unsigned)f2bf(r0) | ((unsigned)f2bf(r1) << 16);
            *(unsigned*)((unsigned short*)Out + (size_t)n * 64 + li * 2) = pk;
        }
    }
}

// ---------------- launch ----------------

extern "C" void kernel_launch(void* const* d_in, const int* in_sizes, int n_in,
                              void* d_out, int out_size, void* d_ws, size_t ws_size,
                              hipStream_t stream) {
    const void* X  = d_in[0];                       // [N,128] bf16 or fp32
    const int*  ei = (const int*)d_in[1];           // [2,E] int32 or int64
    const void* W1 = d_in[2];                       // [128,128]
    const void* W2 = d_in[3];                       // [128,128]
    const void* W3 = d_in[4];                       // [128,64]
    const unsigned short* W1s = (const unsigned short*)W1;

    const int N = in_sizes[0] / 128;   // 50000
    const int E = in_sizes[1] / 2;     // 800000

    char* ws = (char*)d_ws;
    size_t off = 0;
    int* counts = (int*)(ws + off);   off += ws_align((size_t)N * 4);
    int* total  = (int*)(ws + off);   off += ws_align(64);
    const size_t zero_bytes = off;    // counts + total need zeroing
    int2* rc      = (int2*)(ws + off);  off += ws_align((size_t)N * 8);
    float* dinv   = (float*)(ws + off); off += ws_align((size_t)N * 4);
    int* loff     = (int*)(ws + off);   off += ws_align((size_t)E * 4);
    int2* edgedat = (int2*)(ws + off);  off += ws_align((size_t)(E + 64) * 8);
    unsigned short* HA = (unsigned short*)(ws + off); off += ws_align((size_t)N * 128 * 2);
    unsigned short* HB = (unsigned short*)(ws + off); off += ws_align((size_t)N * 128 * 2);

    hipMemsetAsync(d_ws, 0, zero_bytes, stream);

    hist_kernel<<<(E + 255) / 256, 256, 0, stream>>>(ei, counts, loff, E);
    alloc_kernel<<<(N + 255) / 256, 256, 0, stream>>>(counts, dinv, rc, total, N);
    fill_kernel<<<(E + 255) / 256, 256, 0, stream>>>(ei, dinv, rc, loff, edgedat, E);

    const int gblocks = (N + 127) / 128;
    const int waves2 = (N + 1) / 2;                    // 2 nodes per wave
    const int sblocks = (waves2 * 64 + 255) / 256;

    // layer 1: HA = X @ W1 ; HB = relu(A_norm HA)
    gemm_kernel<128><<<gblocks, 256, 0, stream>>>(X, 1, W1, W1s, HA, N);
    spmm128_kernel<<<sblocks, 256, 0, stream>>>(edgedat, rc, HA, HB, N);
    // layer 2
    gemm_kernel<128><<<gblocks, 256, 0, stream>>>(HB, 0, W2, W1s, HA, N);
    spmm128_kernel<<<sblocks, 256, 0, stream>>>(edgedat, rc, HA, HB, N);
    // layer 3 (F_out = 64) + relu + softmax
    gemm_kernel<64><<<gblocks, 256, 0, stream>>>(HB, 0, W3, W1s, HA, N);
    spmm64_softmax_kernel<<<sblocks, 256, 0, stream>>>(edgedat, rc, HA, W1s, d_out, N);
}

// Round 6
// 274.739 us; speedup vs baseline: 1.0491x; 1.0491x over previous
//
#include <hip/hip_runtime.h>
#include <hip/hip_bf16.h>

typedef __attribute__((ext_vector_type(8))) short short8;
typedef __attribute__((ext_vector_type(4))) short short4v;
typedef __attribute__((ext_vector_type(4))) float f32x4;

static inline size_t ws_align(size_t x) { return (x + 511) & ~((size_t)511); }

static __device__ inline unsigned short f2bf(float f) {
    __hip_bfloat16 h = __float2bfloat16(f);
    return __builtin_bit_cast(unsigned short, h);
}
static __device__ inline float bfbits2f(unsigned short u) {
    unsigned x = ((unsigned)u) << 16;
    return __builtin_bit_cast(float, x);
}

// ---------------- inline dtype sniffing (per-wave ballot, no extra kernel) ----------------
static __device__ inline int sniff_fp32(const unsigned short* __restrict__ w1) {
    int i = threadIdx.x & 63;
    unsigned e = (w1[2 * i] >> 7) & 0xFF;
    unsigned long long m = __ballot(e >= 100 && e <= 130);
    return (__popcll(m) < 48) ? 1 : 0;
}
static __device__ inline int sniff_is64(const unsigned int* __restrict__ ei) {
    int i = threadIdx.x & 63;
    unsigned long long m = __ballot(ei[2 * i + 1] == 0u);
    return (__popcll(m) >= 48) ? 1 : 0;
}

// ---------------- CSR build ----------------
// hist: count + record stable local offset per edge (the atomic's return value).
__global__ void hist_kernel(const int* __restrict__ ei,
                            int* __restrict__ counts, int* __restrict__ loff, int E) {
    int is64 = sniff_is64((const unsigned int*)ei);
    int e = blockIdx.x * blockDim.x + threadIdx.x;
    if (e < E) {
        int d = is64 ? ei[2 * (size_t)E + 2 * e] : ei[(size_t)E + e];
        loff[e] = atomicAdd(&counts[d], 1);
    }
}

// fused: dinv + padded segment allocation (wave-scan + one atomic per wave).
// Segments padded to multiple of 8; pad slots stay zero (w=0,src=0) from the memset.
// rc[n] = (start, lenp). Order across waves arbitrary — spmm needs per-node contiguity only.
__global__ __launch_bounds__(256) void alloc_kernel(const int* __restrict__ counts,
                                                    float* __restrict__ dinv,
                                                    int2* __restrict__ rc,
                                                    int* __restrict__ total, int N) {
    int n = blockIdx.x * blockDim.x + threadIdx.x;
    int lane = threadIdx.x & 63;
    int c = (n < N) ? counts[n] : 0;
    if (n < N) {
        int d = (c < 1) ? 1 : c;
        dinv[n] = rsqrtf((float)d);
    }
    int lenp = (c + 7) & ~7;
    int incl = lenp;
#pragma unroll
    for (int off = 1; off < 64; off <<= 1) {
        int v = __shfl_up(incl, off, 64);
        if (lane >= off) incl += v;
    }
    int wavetot = __shfl(incl, 63, 64);
    int base = 0;
    if (lane == 0) base = atomicAdd(total, wavetot);
    base = __shfl(base, 0, 64);
    if (n < N) rc[n] = make_int2(base + incl - lenp, lenp);
}

// atomic-free fill: position = segment start + recorded local offset.
__global__ void fill_kernel(const int* __restrict__ ei,
                            const float* __restrict__ dinv, const int2* __restrict__ rc,
                            const int* __restrict__ loff, int2* __restrict__ edgedat, int E) {
    int is64 = sniff_is64((const unsigned int*)ei);
    int e = blockIdx.x * blockDim.x + threadIdx.x;
    if (e < E) {
        int s, d;
        if (is64) {
            s = ei[2 * e];
            d = ei[2 * (size_t)E + 2 * e];
        } else {
            s = ei[e];
            d = ei[(size_t)E + e];
        }
        int pos = rc[d].x + loff[e];
        float wt = dinv[s] * dinv[d];
        edgedat[pos] = make_int2(s, __float_as_int(wt));
    }
}

// ---------------- GEMM: out[N x FOUT] = A[N x 128] @ W[128 x FOUT], bf16 MFMA ----------------

template <int FOUT>
__global__ __launch_bounds__(256) void gemm_kernel(const void* __restrict__ Araw, int a_follows,
                                                   const void* __restrict__ Wraw,
                                                   const unsigned short* __restrict__ w1sniff,
                                                   unsigned short* __restrict__ out, int Nrows) {
    constexpr int K = 128;
    constexpr int NT = FOUT / 16;
    constexpr int LDB = K + 8;
    __shared__ __align__(16) unsigned short bt[FOUT * LDB];  // bt[n][k] = W[k][n]

    const int tid = threadIdx.x;
    const int in_fp32 = sniff_fp32(w1sniff);
    const int a_fp32 = a_follows & in_fp32;

    constexpr int TOT4 = K * FOUT / 4;
    if (in_fp32) {
        const float* Wf = (const float*)Wraw;
        for (int i = tid; i < TOT4; i += 256) {
            int idx = i * 4;
            int k = idx / FOUT;
            int n = idx & (FOUT - 1);
            float4 v = *(const float4*)(const void*)(Wf + idx);
            bt[(n + 0) * LDB + k] = f2bf(v.x);
            bt[(n + 1) * LDB + k] = f2bf(v.y);
            bt[(n + 2) * LDB + k] = f2bf(v.z);
            bt[(n + 3) * LDB + k] = f2bf(v.w);
        }
    } else {
        const unsigned short* Ws = (const unsigned short*)Wraw;
        for (int i = tid; i < TOT4; i += 256) {
            int idx = i * 4;
            int k = idx / FOUT;
            int n = idx & (FOUT - 1);
            short4v v = *(const short4v*)(const void*)(Ws + idx);
#pragma unroll
            for (int j = 0; j < 4; j++) bt[(n + j) * LDB + k] = ((const unsigned short*)&v)[j];
        }
    }

    const int wave = tid >> 6;
    const int lane = tid & 63;
    const int quad = lane >> 4;
    const int r16 = lane & 15;

    short8 afrag[2][4];
#pragma unroll
    for (int t = 0; t < 2; t++) {
        int arow = blockIdx.x * 128 + t * 64 + wave * 16 + r16;
        if (arow > Nrows - 1) arow = Nrows - 1;
        if (a_fp32) {
            const float* Ap = (const float*)Araw + (size_t)arow * K + quad * 8;
#pragma unroll
            for (int kk = 0; kk < 4; kk++) {
                float4 f0 = *(const float4*)(const void*)(Ap + kk * 32);
                float4 f1 = *(const float4*)(const void*)(Ap + kk * 32 + 4);
                short8 r;
                r[0] = (short)f2bf(f0.x); r[1] = (short)f2bf(f0.y);
                r[2] = (short)f2bf(f0.z); r[3] = (short)f2bf(f0.w);
                r[4] = (short)f2bf(f1.x); r[5] = (short)f2bf(f1.y);
                r[6] = (short)f2bf(f1.z); r[7] = (short)f2bf(f1.w);
                afrag[t][kk] = r;
            }
        } else {
            const unsigned short* Ap = (const unsigned short*)Araw + (size_t)arow * K + quad * 8;
#pragma unroll
            for (int kk = 0; kk < 4; kk++) afrag[t][kk] = *(const short8*)(const void*)(Ap + kk * 32);
        }
    }

    __syncthreads();

    f32x4 acc[2][NT];
#pragma unroll
    for (int t = 0; t < 2; t++)
#pragma unroll
        for (int nt = 0; nt < NT; nt++) acc[t][nt] = (f32x4){0.f, 0.f, 0.f, 0.f};

#pragma unroll
    for (int kk = 0; kk < 4; kk++) {
#pragma unroll
        for (int nt = 0; nt < NT; nt++) {
            short8 b = *(const short8*)(const void*)(&bt[(nt * 16 + r16) * LDB + kk * 32 + quad * 8]);
#pragma unroll
            for (int t = 0; t < 2; t++)
                acc[t][nt] = __builtin_amdgcn_mfma_f32_16x16x32_bf16(afrag[t][kk], b, acc[t][nt], 0, 0, 0);
        }
    }

    // C layout: col = lane&15, row = quad*4 + r. Pack col pairs via shfl_xor; even lanes store bf16x2.
#pragma unroll
    for (int t = 0; t < 2; t++) {
#pragma unroll
        for (int nt = 0; nt < NT; nt++) {
#pragma unroll
            for (int r = 0; r < 4; r++) {
                float v = acc[t][nt][r];
                float o = __shfl_xor(v, 1, 64);
                int row = blockIdx.x * 128 + t * 64 + wave * 16 + quad * 4 + r;
                if (((lane & 1) == 0) && row < Nrows) {
                    __hip_bfloat162 pk;
                    pk.x = __float2bfloat16(v);
                    pk.y = __float2bfloat16(o);
                    *(__hip_bfloat162*)(out + (size_t)row * FOUT + nt * 16 + r16) = pk;
                }
            }
        }
    }
}

// ---------------- SpMM: wave per node, padded CSR -> branch-free 8-wide loop ----------------
// F=128: 64 lanes x bf16x2 (4B) per edge row = 256B coalesced gather.

__global__ __launch_bounds__(256) void spmm128_kernel(const int2* __restrict__ edgedat,
                                                      const int2* __restrict__ rc,
                                                      const __hip_bfloat162* __restrict__ Hin,
                                                      __hip_bfloat162* __restrict__ Hout, int N) {
    int wid = (blockIdx.x * 256 + threadIdx.x) >> 6;
    if (wid >= N) return;
    int lane = threadIdx.x & 63;
    int2 r_ = rc[wid];
    int start = __builtin_amdgcn_readfirstlane(r_.x);
    int lenp  = __builtin_amdgcn_readfirstlane(r_.y);
    const __hip_bfloat162* col = Hin + lane;

    float ax = 0.f, ay = 0.f;
    for (int j = 0; j < lenp; j += 8) {
        int2 ed[8];
#pragma unroll
        for (int u = 0; u < 8; u++) ed[u] = edgedat[start + j + u];
        __hip_bfloat162 hv[8];
#pragma unroll
        for (int u = 0; u < 8; u++) hv[u] = col[(size_t)ed[u].x * 64];
#pragma unroll
        for (int u = 0; u < 8; u++) {
            float w = __int_as_float(ed[u].y);
            ax += w * __bfloat162float(hv[u].x);
            ay += w * __bfloat162float(hv[u].y);
        }
    }
    __hip_bfloat162 pk;
    pk.x = __float2bfloat16(fmaxf(ax, 0.f));
    pk.y = __float2bfloat16(fmaxf(ay, 0.f));
    Hout[(size_t)wid * 64 + lane] = pk;
}

// F=64 + relu + softmax over the 64 lanes (64 classes).
__global__ __launch_bounds__(256) void spmm64_softmax_kernel(const int2* __restrict__ edgedat,
                                                             const int2* __restrict__ rc,
                                                             const unsigned short* __restrict__ Hin,
                                                             const unsigned short* __restrict__ w1sniff,
                                                             void* __restrict__ Out, int N) {
    int out_fp32 = sniff_fp32(w1sniff);
    int wid = (blockIdx.x * 256 + threadIdx.x) >> 6;
    if (wid >= N) return;
    int lane = threadIdx.x & 63;
    int2 r_ = rc[wid];
    int start = __builtin_amdgcn_readfirstlane(r_.x);
    int lenp  = __builtin_amdgcn_readfirstlane(r_.y);
    const unsigned short* col = Hin + lane;

    float a = 0.f;
    for (int j = 0; j < lenp; j += 8) {
        int2 ed[8];
#pragma unroll
        for (int u = 0; u < 8; u++) ed[u] = edgedat[start + j + u];
        float hv[8];
#pragma unroll
        for (int u = 0; u < 8; u++) hv[u] = bfbits2f(col[(size_t)ed[u].x * 64]);
#pragma unroll
        for (int u = 0; u < 8; u++) a += __int_as_float(ed[u].y) * hv[u];
    }
    a = fmaxf(a, 0.f);   // relu
    float m = a;
#pragma unroll
    for (int off = 32; off > 0; off >>= 1) m = fmaxf(m, __shfl_xor(m, off, 64));
    float e = __expf(a - m);
    float s = e;
#pragma unroll
    for (int off = 32; off > 0; off >>= 1) s += __shfl_xor(s, off, 64);
    float r = e / s;
    if (out_fp32) {
        ((float*)Out)[(size_t)wid * 64 + lane] = r;
    } else {
        ((unsigned short*)Out)[(size_t)wid * 64 + lane] = f2bf(r);
    }
}

// ---------------- launch ----------------

extern "C" void kernel_launch(void* const* d_in, const int* in_sizes, int n_in,
                              void* d_out, int out_size, void* d_ws, size_t ws_size,
                              hipStream_t stream) {
    const void* X  = d_in[0];                       // [N,128] bf16 or fp32
    const int*  ei = (const int*)d_in[1];           // [2,E] int32 or int64
    const void* W1 = d_in[2];                       // [128,128]
    const void* W2 = d_in[3];                       // [128,128]
    const void* W3 = d_in[4];                       // [128,64]
    const unsigned short* W1s = (const unsigned short*)W1;

    const int N = in_sizes[0] / 128;   // 50000
    const int E = in_sizes[1] / 2;     // 800000

    const size_t edgecap = (size_t)E + 8 * (size_t)N + 64;  // padded-CSR slot capacity

    char* ws = (char*)d_ws;
    size_t off = 0;
    int* counts = (int*)(ws + off);   off += ws_align((size_t)N * 4);
    int* total  = (int*)(ws + off);   off += ws_align(64);
    const size_t zero_bytes = off;    // counts + total need zeroing
    int2* rc      = (int2*)(ws + off);  off += ws_align((size_t)N * 8);
    float* dinv   = (float*)(ws + off); off += ws_align((size_t)N * 4);
    int* loff     = (int*)(ws + off);   off += ws_align((size_t)E * 4);
    int2* edgedat = (int2*)(ws + off);  off += ws_align(edgecap * 8);
    unsigned short* HA = (unsigned short*)(ws + off); off += ws_align((size_t)N * 128 * 2);
    unsigned short* HB = (unsigned short*)(ws + off); off += ws_align((size_t)N * 128 * 2);

    hipMemsetAsync(d_ws, 0, zero_bytes, stream);
    hipMemsetAsync(edgedat, 0, edgecap * 8, stream);   // pad slots: src=0, w=0

    hist_kernel<<<(E + 255) / 256, 256, 0, stream>>>(ei, counts, loff, E);
    alloc_kernel<<<(N + 255) / 256, 256, 0, stream>>>(counts, dinv, rc, total, N);
    fill_kernel<<<(E + 255) / 256, 256, 0, stream>>>(ei, dinv, rc, loff, edgedat, E);

    const int gblocks = (N + 127) / 128;
    const int sblocks = ((size_t)N * 64 + 255) / 256;   // one wave per node

    // layer 1: HA = X @ W1 ; HB = relu(A_norm HA)
    gemm_kernel<128><<<gblocks, 256, 0, stream>>>(X, 1, W1, W1s, HA, N);
    spmm128_kernel<<<sblocks, 256, 0, stream>>>(edgedat, rc, (const __hip_bfloat162*)HA,
                                                (__hip_bfloat162*)HB, N);
    // layer 2
    gemm_kernel<128><<<gblocks, 256, 0, stream>>>(HB, 0, W2, W1s, HA, N);
    spmm128_kernel<<<sblocks, 256, 0, stream>>>(edgedat, rc, (const __hip_bfloat162*)HA,
                                                (__hip_bfloat162*)HB, N);
    // layer 3 (F_out = 64) + relu + softmax
    gemm_kernel<64><<<gblocks, 256, 0, stream>>>(HB, 0, W3, W1s, HA, N);
    spmm64_softmax_kernel<<<sblocks, 256, 0, stream>>>(edgedat, rc, HA, W1s, d_out, N);
}

// Round 7
// 273.044 us; speedup vs baseline: 1.0557x; 1.0062x over previous
//
#include <hip/hip_runtime.h>
#include <hip/hip_bf16.h>

typedef __attribute__((ext_vector_type(8))) short short8;
typedef __attribute__((ext_vector_type(4))) short short4v;
typedef __attribute__((ext_vector_type(4))) float f32x4;

static inline size_t ws_align(size_t x) { return (x + 511) & ~((size_t)511); }

static __device__ inline unsigned short f2bf(float f) {
    __hip_bfloat16 h = __float2bfloat16(f);
    return __builtin_bit_cast(unsigned short, h);
}
static __device__ inline float bfbits2f(unsigned short u) {
    unsigned x = ((unsigned)u) << 16;
    return __builtin_bit_cast(float, x);
}

// ---------------- inline dtype sniffing (per-wave ballot, no extra kernel) ----------------
static __device__ inline int sniff_fp32(const unsigned short* __restrict__ w1) {
    int i = threadIdx.x & 63;
    unsigned e = (w1[2 * i] >> 7) & 0xFF;
    unsigned long long m = __ballot(e >= 100 && e <= 130);
    return (__popcll(m) < 48) ? 1 : 0;
}
static __device__ inline int sniff_is64(const unsigned int* __restrict__ ei) {
    int i = threadIdx.x & 63;
    unsigned long long m = __ballot(ei[2 * i + 1] == 0u);
    return (__popcll(m) >= 48) ? 1 : 0;
}

// ---------------- GEMM body: out[N x FOUT] = A[N x 128] @ W[128 x FOUT], bf16 MFMA ----------------
// 256 threads = 4 waves; each wave computes 2 row-tiles of 16 -> 128 rows per "bid".

template <int FOUT>
static __device__ void gemm_body(const void* __restrict__ Araw, int a_follows,
                                 const void* __restrict__ Wraw,
                                 const unsigned short* __restrict__ w1sniff,
                                 unsigned short* __restrict__ out, int Nrows, int bid) {
    constexpr int K = 128;
    constexpr int NT = FOUT / 16;
    constexpr int LDB = K + 8;
    __shared__ __align__(16) unsigned short bt[FOUT * LDB];  // bt[n][k] = W[k][n]

    const int tid = threadIdx.x;
    const int in_fp32 = sniff_fp32(w1sniff);
    const int a_fp32 = a_follows & in_fp32;

    constexpr int TOT4 = K * FOUT / 4;
    if (in_fp32) {
        const float* Wf = (const float*)Wraw;
        for (int i = tid; i < TOT4; i += 256) {
            int idx = i * 4;
            int k = idx / FOUT;
            int n = idx & (FOUT - 1);
            float4 v = *(const float4*)(const void*)(Wf + idx);
            bt[(n + 0) * LDB + k] = f2bf(v.x);
            bt[(n + 1) * LDB + k] = f2bf(v.y);
            bt[(n + 2) * LDB + k] = f2bf(v.z);
            bt[(n + 3) * LDB + k] = f2bf(v.w);
        }
    } else {
        const unsigned short* Ws = (const unsigned short*)Wraw;
        for (int i = tid; i < TOT4; i += 256) {
            int idx = i * 4;
            int k = idx / FOUT;
            int n = idx & (FOUT - 1);
            short4v v = *(const short4v*)(const void*)(Ws + idx);
#pragma unroll
            for (int j = 0; j < 4; j++) bt[(n + j) * LDB + k] = ((const unsigned short*)&v)[j];
        }
    }

    const int wave = tid >> 6;
    const int lane = tid & 63;
    const int quad = lane >> 4;
    const int r16 = lane & 15;

    short8 afrag[2][4];
#pragma unroll
    for (int t = 0; t < 2; t++) {
        int arow = bid * 128 + t * 64 + wave * 16 + r16;
        if (arow > Nrows - 1) arow = Nrows - 1;
        if (a_fp32) {
            const float* Ap = (const float*)Araw + (size_t)arow * K + quad * 8;
#pragma unroll
            for (int kk = 0; kk < 4; kk++) {
                float4 f0 = *(const float4*)(const void*)(Ap + kk * 32);
                float4 f1 = *(const float4*)(const void*)(Ap + kk * 32 + 4);
                short8 r;
                r[0] = (short)f2bf(f0.x); r[1] = (short)f2bf(f0.y);
                r[2] = (short)f2bf(f0.z); r[3] = (short)f2bf(f0.w);
                r[4] = (short)f2bf(f1.x); r[5] = (short)f2bf(f1.y);
                r[6] = (short)f2bf(f1.z); r[7] = (short)f2bf(f1.w);
                afrag[t][kk] = r;
            }
        } else {
            const unsigned short* Ap = (const unsigned short*)Araw + (size_t)arow * K + quad * 8;
#pragma unroll
            for (int kk = 0; kk < 4; kk++) afrag[t][kk] = *(const short8*)(const void*)(Ap + kk * 32);
        }
    }

    __syncthreads();

    f32x4 acc[2][NT];
#pragma unroll
    for (int t = 0; t < 2; t++)
#pragma unroll
        for (int nt = 0; nt < NT; nt++) acc[t][nt] = (f32x4){0.f, 0.f, 0.f, 0.f};

#pragma unroll
    for (int kk = 0; kk < 4; kk++) {
#pragma unroll
        for (int nt = 0; nt < NT; nt++) {
            short8 b = *(const short8*)(const void*)(&bt[(nt * 16 + r16) * LDB + kk * 32 + quad * 8]);
#pragma unroll
            for (int t = 0; t < 2; t++)
                acc[t][nt] = __builtin_amdgcn_mfma_f32_16x16x32_bf16(afrag[t][kk], b, acc[t][nt], 0, 0, 0);
        }
    }

    // C layout: col = lane&15, row = quad*4 + r. Pack col pairs via shfl_xor; even lanes store bf16x2.
#pragma unroll
    for (int t = 0; t < 2; t++) {
#pragma unroll
        for (int nt = 0; nt < NT; nt++) {
#pragma unroll
            for (int r = 0; r < 4; r++) {
                float v = acc[t][nt][r];
                float o = __shfl_xor(v, 1, 64);
                int row = bid * 128 + t * 64 + wave * 16 + quad * 4 + r;
                if (((lane & 1) == 0) && row < Nrows) {
                    __hip_bfloat162 pk;
                    pk.x = __float2bfloat16(v);
                    pk.y = __float2bfloat16(o);
                    *(__hip_bfloat162*)(out + (size_t)row * FOUT + nt * 16 + r16) = pk;
                }
            }
        }
    }
}

template <int FOUT>
__global__ __launch_bounds__(256) void gemm_kernel(const void* __restrict__ Araw, int a_follows,
                                                   const void* __restrict__ Wraw,
                                                   const unsigned short* __restrict__ w1sniff,
                                                   unsigned short* __restrict__ out, int Nrows) {
    gemm_body<FOUT>(Araw, a_follows, Wraw, w1sniff, out, Nrows, blockIdx.x);
}

// ---------------- heterogeneous launch: gemm1 (X@W1) blocks + hist blocks ----------------
// gemm1 is independent of the CSR build, so it runs under hist's atomic shadow.
__global__ __launch_bounds__(256) void gemm1_hist_kernel(const void* __restrict__ X,
                                                         const void* __restrict__ W1,
                                                         const unsigned short* __restrict__ w1sniff,
                                                         unsigned short* __restrict__ HA, int N,
                                                         const int* __restrict__ ei,
                                                         int* __restrict__ counts,
                                                         int* __restrict__ loff, int E, int gblocks) {
    if ((int)blockIdx.x < gblocks) {
        gemm_body<128>(X, 1, W1, w1sniff, HA, N, blockIdx.x);
    } else {
        int is64 = sniff_is64((const unsigned int*)ei);
        int e = ((int)blockIdx.x - gblocks) * 256 + threadIdx.x;
        if (e < E) {
            int d = is64 ? ei[2 * (size_t)E + 2 * e] : ei[(size_t)E + e];
            loff[e] = atomicAdd(&counts[d], 1);
        }
    }
}

// fused: dinv + padded segment allocation (wave-scan + one atomic per wave).
// Segments padded to multiple of 16; pad slots stay zero (w=0,src=0) from the memset.
__global__ __launch_bounds__(256) void alloc_kernel(const int* __restrict__ counts,
                                                    float* __restrict__ dinv,
                                                    int2* __restrict__ rc,
                                                    int* __restrict__ total, int N) {
    int n = blockIdx.x * blockDim.x + threadIdx.x;
    int lane = threadIdx.x & 63;
    int c = (n < N) ? counts[n] : 0;
    if (n < N) {
        int d = (c < 1) ? 1 : c;
        dinv[n] = rsqrtf((float)d);
    }
    int lenp = (c + 15) & ~15;
    int incl = lenp;
#pragma unroll
    for (int off = 1; off < 64; off <<= 1) {
        int v = __shfl_up(incl, off, 64);
        if (lane >= off) incl += v;
    }
    int wavetot = __shfl(incl, 63, 64);
    int base = 0;
    if (lane == 0) base = atomicAdd(total, wavetot);
    base = __shfl(base, 0, 64);
    if (n < N) rc[n] = make_int2(base + incl - lenp, lenp);
}

// atomic-free fill: position = segment start + recorded local offset.
__global__ void fill_kernel(const int* __restrict__ ei,
                            const float* __restrict__ dinv, const int2* __restrict__ rc,
                            const int* __restrict__ loff, int2* __restrict__ edgedat, int E) {
    int is64 = sniff_is64((const unsigned int*)ei);
    int e = blockIdx.x * blockDim.x + threadIdx.x;
    if (e < E) {
        int s, d;
        if (is64) {
            s = ei[2 * e];
            d = ei[2 * (size_t)E + 2 * e];
        } else {
            s = ei[e];
            d = ei[(size_t)E + e];
        }
        int pos = rc[d].x + loff[e];
        float wt = dinv[s] * dinv[d];
        edgedat[pos] = make_int2(s, __float_as_int(wt));
    }
}

// ---------------- SpMM: wave per node, padded CSR -> branch-free 16-deep pipeline ----------------
// F=128: 64 lanes x bf16x2 (4B) per edge row = 256B coalesced gather; 16 gathers in flight.

__global__ __launch_bounds__(256) void spmm128_kernel(const int2* __restrict__ edgedat,
                                                      const int2* __restrict__ rc,
                                                      const __hip_bfloat162* __restrict__ Hin,
                                                      __hip_bfloat162* __restrict__ Hout, int N) {
    int wid = (blockIdx.x * 256 + threadIdx.x) >> 6;
    if (wid >= N) return;
    int lane = threadIdx.x & 63;
    int2 r_ = rc[wid];
    int start = __builtin_amdgcn_readfirstlane(r_.x);
    int lenp  = __builtin_amdgcn_readfirstlane(r_.y);
    const __hip_bfloat162* col = Hin + lane;

    float ax = 0.f, ay = 0.f;
    for (int j = 0; j < lenp; j += 16) {
        int2 ed[16];
#pragma unroll
        for (int u = 0; u < 16; u++) ed[u] = edgedat[start + j + u];
        __hip_bfloat162 hv[16];
#pragma unroll
        for (int u = 0; u < 16; u++) hv[u] = col[(size_t)ed[u].x * 64];
#pragma unroll
        for (int u = 0; u < 16; u++) {
            float w = __int_as_float(ed[u].y);
            ax += w * __bfloat162float(hv[u].x);
            ay += w * __bfloat162float(hv[u].y);
        }
    }
    __hip_bfloat162 pk;
    pk.x = __float2bfloat16(fmaxf(ax, 0.f));
    pk.y = __float2bfloat16(fmaxf(ay, 0.f));
    Hout[(size_t)wid * 64 + lane] = pk;
}

// F=64 + relu + softmax over the 64 lanes (64 classes).
__global__ __launch_bounds__(256) void spmm64_softmax_kernel(const int2* __restrict__ edgedat,
                                                             const int2* __restrict__ rc,
                                                             const unsigned short* __restrict__ Hin,
                                                             const unsigned short* __restrict__ w1sniff,
                                                             void* __restrict__ Out, int N) {
    int out_fp32 = sniff_fp32(w1sniff);
    int wid = (blockIdx.x * 256 + threadIdx.x) >> 6;
    if (wid >= N) return;
    int lane = threadIdx.x & 63;
    int2 r_ = rc[wid];
    int start = __builtin_amdgcn_readfirstlane(r_.x);
    int lenp  = __builtin_amdgcn_readfirstlane(r_.y);
    const unsigned short* col = Hin + lane;

    float a = 0.f;
    for (int j = 0; j < lenp; j += 16) {
        int2 ed[16];
#pragma unroll
        for (int u = 0; u < 16; u++) ed[u] = edgedat[start + j + u];
        float hv[16];
#pragma unroll
        for (int u = 0; u < 16; u++) hv[u] = bfbits2f(col[(size_t)ed[u].x * 64]);
#pragma unroll
        for (int u = 0; u < 16; u++) a += __int_as_float(ed[u].y) * hv[u];
    }
    a = fmaxf(a, 0.f);   // relu
    float m = a;
#pragma unroll
    for (int off = 32; off > 0; off >>= 1) m = fmaxf(m, __shfl_xor(m, off, 64));
    float e = __expf(a - m);
    float s = e;
#pragma unroll
    for (int off = 32; off > 0; off >>= 1) s += __shfl_xor(s, off, 64);
    float r = e / s;
    if (out_fp32) {
        ((float*)Out)[(size_t)wid * 64 + lane] = r;
    } else {
        ((unsigned short*)Out)[(size_t)wid * 64 + lane] = f2bf(r);
    }
}

// ---------------- launch ----------------

extern "C" void kernel_launch(void* const* d_in, const int* in_sizes, int n_in,
                              void* d_out, int out_size, void* d_ws, size_t ws_size,
                              hipStream_t stream) {
    const void* X  = d_in[0];                       // [N,128] bf16 or fp32
    const int*  ei = (const int*)d_in[1];           // [2,E] int32 or int64
    const void* W1 = d_in[2];                       // [128,128]
    const void* W2 = d_in[3];                       // [128,128]
    const void* W3 = d_in[4];                       // [128,64]
    const unsigned short* W1s = (const unsigned short*)W1;

    const int N = in_sizes[0] / 128;   // 50000
    const int E = in_sizes[1] / 2;     // 800000

    const size_t edgecap = (size_t)E + 16 * (size_t)N + 64;  // padded-CSR slot capacity

    char* ws = (char*)d_ws;
    size_t off = 0;
    int* counts = (int*)(ws + off);   off += ws_align((size_t)N * 4);
    int* total  = (int*)(ws + off);   off += ws_align(64);
    const size_t zero_bytes = off;    // counts + total need zeroing
    int2* rc      = (int2*)(ws + off);  off += ws_align((size_t)N * 8);
    float* dinv   = (float*)(ws + off); off += ws_align((size_t)N * 4);
    int* loff     = (int*)(ws + off);   off += ws_align((size_t)E * 4);
    int2* edgedat = (int2*)(ws + off);  off += ws_align(edgecap * 8);
    unsigned short* HA = (unsigned short*)(ws + off); off += ws_align((size_t)N * 128 * 2);
    unsigned short* HB = (unsigned short*)(ws + off); off += ws_align((size_t)N * 128 * 2);

    hipMemsetAsync(d_ws, 0, zero_bytes, stream);
    hipMemsetAsync(edgedat, 0, edgecap * 8, stream);   // pad slots: src=0, w=0

    const int gblocks = (N + 127) / 128;
    const int hblocks = (E + 255) / 256;
    const int sblocks = ((size_t)N * 64 + 255) / 256;   // one wave per node

    // K1: gemm1 (X@W1 -> HA) overlapped with hist (CSR counts + per-edge slot)
    gemm1_hist_kernel<<<gblocks + hblocks, 256, 0, stream>>>(X, W1, W1s, HA, N,
                                                             ei, counts, loff, E, gblocks);
    alloc_kernel<<<(N + 255) / 256, 256, 0, stream>>>(counts, dinv, rc, total, N);
    fill_kernel<<<hblocks, 256, 0, stream>>>(ei, dinv, rc, loff, edgedat, E);

    // layer 1 aggregate: HB = relu(A_norm HA)
    spmm128_kernel<<<sblocks, 256, 0, stream>>>(edgedat, rc, (const __hip_bfloat162*)HA,
                                                (__hip_bfloat162*)HB, N);
    // layer 2
    gemm_kernel<128><<<gblocks, 256, 0, stream>>>(HB, 0, W2, W1s, HA, N);
    spmm128_kernel<<<sblocks, 256, 0, stream>>>(edgedat, rc, (const __hip_bfloat162*)HA,
                                                (__hip_bfloat162*)HB, N);
    // layer 3 (F_out = 64) + relu + softmax
    gemm_kernel<64><<<gblocks, 256, 0, stream>>>(HB, 0, W3, W1s, HA, N);
    spmm64_softmax_kernel<<<sblocks, 256, 0, stream>>>(edgedat, rc, HA, W1s, d_out, N);
}